// Round 1
// baseline (299.977 us; speedup 1.0000x reference)
//
#include <hip/hip_runtime.h>
#include <hip/hip_bf16.h>

// Sizes fixed by the problem
#define BB 8
#define NN 1024
#define DD 256
#define RR 12
#define BN (BB * NN)          // 8192

// ---------------- Kernel A: Wh = h @ W  (f32 tiled GEMM) ----------------
// M=8192, N=256, K=256. Tile 64x64, K-step 16, 256 threads, 4x4 per thread.
__global__ __launch_bounds__(256) void k_gemm_hW(const float* __restrict__ A,
                                                 const float* __restrict__ W,
                                                 float* __restrict__ C) {
  int d0 = blockIdx.x * 64;
  int i0 = blockIdx.y * 64;
  __shared__ float As[16][68];
  __shared__ float Bs[16][68];
  int tid = threadIdx.x;
  int tx = tid & 15, ty = tid >> 4;
  float acc[4][4] = {};
  for (int k0 = 0; k0 < DD; k0 += 16) {
    {
      int ii = tid >> 2, kk = (tid & 3) * 4;
      float4 v = *(const float4*)&A[(i0 + ii) * DD + k0 + kk];
      As[kk + 0][ii] = v.x; As[kk + 1][ii] = v.y;
      As[kk + 2][ii] = v.z; As[kk + 3][ii] = v.w;
    }
    {
      int kk = tid >> 4, dd = (tid & 15) * 4;
      *(float4*)&Bs[kk][dd] = *(const float4*)&W[(k0 + kk) * DD + d0 + dd];
    }
    __syncthreads();
#pragma unroll
    for (int k = 0; k < 16; ++k) {
      float4 a4 = *(const float4*)&As[k][ty * 4];
      float4 b4 = *(const float4*)&Bs[k][tx * 4];
      float av[4] = {a4.x, a4.y, a4.z, a4.w};
      float bv[4] = {b4.x, b4.y, b4.z, b4.w};
#pragma unroll
      for (int mi = 0; mi < 4; ++mi)
#pragma unroll
        for (int ni = 0; ni < 4; ++ni) acc[mi][ni] += av[mi] * bv[ni];
    }
    __syncthreads();
  }
#pragma unroll
  for (int mi = 0; mi < 4; ++mi) {
    float4 o = make_float4(acc[mi][0], acc[mi][1], acc[mi][2], acc[mi][3]);
    *(float4*)&C[(i0 + ty * 4 + mi) * DD + d0 + tx * 4] = o;
  }
}

// ---------------- Kernel A2: per-node projections ----------------
// s0[bn]=Wh0·a[:D], s1[bn]=Wh1·a[D:], r0[r,bn]=Wh0·A_rel[r,:D], r1[r,bn]=Wh1·A_rel[r,D:]
__global__ __launch_bounds__(256) void k_proj(const float* __restrict__ Wh0,
                                              const float* __restrict__ Wh1,
                                              const float* __restrict__ a,
                                              const float* __restrict__ A_rel,
                                              float* __restrict__ s0, float* __restrict__ s1,
                                              float* __restrict__ r0, float* __restrict__ r1) {
  int wid = (blockIdx.x * 256 + threadIdx.x) >> 6;  // 0..16383
  int lane = threadIdx.x & 63;
  int mat = wid >> 13;
  int row = wid & (BN - 1);
  const float* Wh = mat ? Wh1 : Wh0;
  float4 h4 = *(const float4*)&Wh[row * DD + lane * 4];
  {
    float4 v4 = *(const float4*)&a[mat * DD + lane * 4];
    float p = h4.x * v4.x + h4.y * v4.y + h4.z * v4.z + h4.w * v4.w;
#pragma unroll
    for (int off = 32; off; off >>= 1) p += __shfl_xor(p, off);
    if (lane == 0) (mat ? s1 : s0)[row] = p;
  }
  for (int r = 0; r < RR; ++r) {
    float4 w4 = *(const float4*)&A_rel[r * 2 * DD + mat * DD + lane * 4];
    float q = h4.x * w4.x + h4.y * w4.y + h4.z * w4.z + h4.w * w4.w;
#pragma unroll
    for (int off = 32; off; off >>= 1) q += __shfl_xor(q, off);
    if (lane == 0) (mat ? r1 : r0)[r * BN + row] = q;
  }
}

// ---------------- Kernel B: scores + partial column-softmax stats ----------------
// Each thread owns 2 columns j, streams an i-chunk, online (m,l), writes raw S.
#define ICH 16
#define CCH 64
__global__ __launch_bounds__(128) void k_scores(const int* __restrict__ madj,
                                                const int* __restrict__ adj,
                                                const float* __restrict__ s0,
                                                const float* __restrict__ s1,
                                                const float* __restrict__ r0,
                                                const float* __restrict__ r1,
                                                float* __restrict__ S,
                                                float* __restrict__ pm,
                                                float* __restrict__ pl) {
  // grid (NN/256, BB, CCH)
  int b = blockIdx.y, c = blockIdx.z;
  int j = blockIdx.x * 256 + threadIdx.x * 2;
  int i0 = c * ICH;
  __shared__ float s0c[ICH];
  __shared__ float r0c[RR][ICH];
  for (int t = threadIdx.x; t < (RR + 1) * ICH; t += 128) {
    int v = t / ICH, i = t % ICH;
    float x = (v == 0) ? s0[b * NN + i0 + i] : r0[(v - 1) * BN + b * NN + i0 + i];
    if (v == 0) s0c[i] = x; else r0c[v - 1][i] = x;
  }
  __syncthreads();
  float s1a = s1[b * NN + j], s1b = s1[b * NN + j + 1];
  float r1a[RR], r1b[RR];
#pragma unroll
  for (int r = 0; r < RR; ++r) {
    r1a[r] = r1[r * BN + b * NN + j];
    r1b[r] = r1[r * BN + b * NN + j + 1];
  }
  float m0 = -3.0e38f, l0 = 0.f, m1 = -3.0e38f, l1 = 0.f;
  for (int i = 0; i < ICH; ++i) {
    int ii = i0 + i;
    int base = (b * NN + ii) * NN + j;
    int2 av = *(const int2*)&adj[base];
    float s0v = s0c[i];
    float e0 = s0v + s1a; e0 = e0 >= 0.f ? e0 : 0.2f * e0;
    float e1 = s0v + s1b; e1 = e1 >= 0.f ? e1 : 0.2f * e1;
    float sc0 = av.x > 0 ? e0 : -9e15f;
    float sc1 = av.y > 0 ? e1 : -9e15f;
    float rel0 = 0.f, rel1 = 0.f;
#pragma unroll
    for (int r = 0; r < RR; ++r) {
      int2 mv = *(const int2*)&madj[((r * BB + b) * NN + ii) * NN + j];
      float t0 = r0c[r][i] + r1a[r]; t0 = t0 >= 0.f ? t0 : 0.2f * t0;
      float t1 = r0c[r][i] + r1b[r]; t1 = t1 >= 0.f ? t1 : 0.2f * t1;
      if (mv.x > 0) rel0 += t0;
      if (mv.y > 0) rel1 += t1;
    }
    sc0 += 0.01f * rel0;
    sc1 += 0.01f * rel1;
    *(float2*)&S[base] = make_float2(sc0, sc1);
    float nm0 = fmaxf(m0, sc0);
    l0 = l0 * __expf(m0 - nm0) + __expf(sc0 - nm0); m0 = nm0;
    float nm1 = fmaxf(m1, sc1);
    l1 = l1 * __expf(m1 - nm1) + __expf(sc1 - nm1); m1 = nm1;
  }
  int col = b * NN + j;
  *(float2*)&pm[c * BN + col] = make_float2(m0, m1);
  *(float2*)&pl[c * BN + col] = make_float2(l0, l1);
}

// ---------------- Kernel B2: combine partial stats ----------------
__global__ __launch_bounds__(256) void k_combine(const float* __restrict__ pm,
                                                 const float* __restrict__ pl,
                                                 float* __restrict__ mf,
                                                 float* __restrict__ li) {
  int col = blockIdx.x * 256 + threadIdx.x;  // 0..8191
  float m = -3.0e38f;
  for (int c = 0; c < CCH; ++c) m = fmaxf(m, pm[c * BN + col]);
  float l = 0.f;
  for (int c = 0; c < CCH; ++c) l += pl[c * BN + col] * __expf(pm[c * BN + col] - m);
  mf[col] = m;
  li[col] = 1.0f / l;
}

// ---------------- Kernel C: out = elu( P @ Wh1 ),  P = exp(S - m_col)/l_col ----------------
// Per b: M=1024 (i), N=256 (d), K=1024 (j). Tile 64x64, K-step 16.
__global__ __launch_bounds__(256) void k_av(const float* __restrict__ S,
                                            const float* __restrict__ mf,
                                            const float* __restrict__ li,
                                            const float* __restrict__ Wh1,
                                            float* __restrict__ out) {
  int b = blockIdx.z;
  int i0 = blockIdx.y * 64;
  int d0 = blockIdx.x * 64;
  __shared__ float Ps[16][68];
  __shared__ float Vs[16][68];
  int tid = threadIdx.x;
  int tx = tid & 15, ty = tid >> 4;
  float acc[4][4] = {};
  for (int k0 = 0; k0 < NN; k0 += 16) {
    {
      int ii = tid >> 2, kk = (tid & 3) * 4;
      float4 sv = *(const float4*)&S[(b * NN + i0 + ii) * NN + k0 + kk];
      float4 mv = *(const float4*)&mf[b * NN + k0 + kk];
      float4 lv = *(const float4*)&li[b * NN + k0 + kk];
      Ps[kk + 0][ii] = __expf(sv.x - mv.x) * lv.x;
      Ps[kk + 1][ii] = __expf(sv.y - mv.y) * lv.y;
      Ps[kk + 2][ii] = __expf(sv.z - mv.z) * lv.z;
      Ps[kk + 3][ii] = __expf(sv.w - mv.w) * lv.w;
    }
    {
      int kk = tid >> 4, dd = (tid & 15) * 4;
      *(float4*)&Vs[kk][dd] = *(const float4*)&Wh1[(b * NN + k0 + kk) * DD + d0 + dd];
    }
    __syncthreads();
#pragma unroll
    for (int k = 0; k < 16; ++k) {
      float4 a4 = *(const float4*)&Ps[k][ty * 4];
      float4 b4 = *(const float4*)&Vs[k][tx * 4];
      float av[4] = {a4.x, a4.y, a4.z, a4.w};
      float bv[4] = {b4.x, b4.y, b4.z, b4.w};
#pragma unroll
      for (int mi = 0; mi < 4; ++mi)
#pragma unroll
        for (int ni = 0; ni < 4; ++ni) acc[mi][ni] += av[mi] * bv[ni];
    }
    __syncthreads();
  }
#pragma unroll
  for (int mi = 0; mi < 4; ++mi) {
    float o[4];
#pragma unroll
    for (int ni = 0; ni < 4; ++ni) {
      float x = acc[mi][ni];
      o[ni] = x > 0.f ? x : expm1f(x);
    }
    *(float4*)&out[(b * NN + i0 + ty * 4 + mi) * DD + d0 + tx * 4] =
        make_float4(o[0], o[1], o[2], o[3]);
  }
}

extern "C" void kernel_launch(void* const* d_in, const int* in_sizes, int n_in,
                              void* d_out, int out_size, void* d_ws, size_t ws_size,
                              hipStream_t stream) {
  const float* h0 = (const float*)d_in[0];
  const float* h1 = (const float*)d_in[1];
  const int* madj = (const int*)d_in[2];
  const int* adj = (const int*)d_in[3];
  const float* W = (const float*)d_in[4];
  const float* a = (const float*)d_in[5];
  const float* A_rel = (const float*)d_in[6];
  float* out = (float*)d_out;

  float* ws = (float*)d_ws;
  float* Wh0 = ws;                       // 2,097,152
  float* Wh1 = Wh0 + (size_t)BN * DD;    // 2,097,152
  float* S   = Wh1 + (size_t)BN * DD;    // 8,388,608
  float* s0  = S + (size_t)BB * NN * NN; // 8192
  float* s1  = s0 + BN;
  float* r0  = s1 + BN;                  // 12*8192
  float* r1  = r0 + RR * BN;
  float* pm  = r1 + RR * BN;             // CCH*8192
  float* pl  = pm + (size_t)CCH * BN;
  float* mf  = pl + (size_t)CCH * BN;    // 8192
  float* li  = mf + BN;

  k_gemm_hW<<<dim3(DD / 64, BN / 64), 256, 0, stream>>>(h0, W, Wh0);
  k_gemm_hW<<<dim3(DD / 64, BN / 64), 256, 0, stream>>>(h1, W, Wh1);
  k_proj<<<(2 * BN) / 4, 256, 0, stream>>>(Wh0, Wh1, a, A_rel, s0, s1, r0, r1);
  k_scores<<<dim3(NN / 256, BB, CCH), 128, 0, stream>>>(madj, adj, s0, s1, r0, r1, S, pm, pl);
  k_combine<<<BN / 256, 256, 0, stream>>>(pm, pl, mf, li);
  k_av<<<dim3(DD / 64, NN / 64, BB), 256, 0, stream>>>(S, mf, li, Wh1, out);
}

// Round 2
// 238.517 us; speedup vs baseline: 1.2577x; 1.2577x over previous
//
#include <hip/hip_runtime.h>
#include <hip/hip_bf16.h>

#define BB 8
#define NN 1024
#define DD 256
#define RR 12
#define BN (BB * NN)  // 8192

typedef __attribute__((ext_vector_type(8))) short short8v;
typedef __attribute__((ext_vector_type(4))) float f32x4;

static __device__ __forceinline__ ushort f2bf(float f) {
  union { float f; uint u; } v; v.f = f;
  uint r = v.u + 0x7FFF + ((v.u >> 16) & 1);
  return (ushort)(r >> 16);
}
static __device__ __forceinline__ uint pack2(float a, float b) {
  return (uint)f2bf(a) | ((uint)f2bf(b) << 16);
}

// ---------------- prep: WTb[d][k] = bf16(W[k][d]) ----------------
__global__ __launch_bounds__(256) void k_prepW(const float* __restrict__ W,
                                               ushort* __restrict__ WTb) {
  __shared__ float Ls[64][65];
  int k0 = blockIdx.x * 64, d0 = blockIdx.y * 64;
  int tid = threadIdx.x;
  int rr = tid >> 4, c = (tid & 15) * 4;
#pragma unroll
  for (int p = 0; p < 4; ++p) {
    int row = p * 16 + rr;
    float4 v = *(const float4*)&W[(k0 + row) * DD + d0 + c];
    Ls[row][c] = v.x; Ls[row][c + 1] = v.y; Ls[row][c + 2] = v.z; Ls[row][c + 3] = v.w;
  }
  __syncthreads();
  int r2 = tid >> 3, cc = (tid & 7) * 8;
#pragma unroll
  for (int p = 0; p < 2; ++p) {
    int d = p * 32 + r2;
    uint4 q;
    q.x = pack2(Ls[cc + 0][d], Ls[cc + 1][d]);
    q.y = pack2(Ls[cc + 2][d], Ls[cc + 3][d]);
    q.z = pack2(Ls[cc + 4][d], Ls[cc + 5][d]);
    q.w = pack2(Ls[cc + 6][d], Ls[cc + 7][d]);
    *(uint4*)&WTb[(d0 + d) * DD + k0 + cc] = q;
  }
}

// ---------------- prep: WhbT[b][d][i] = bf16(Wh1[b][i][d]) ----------------
__global__ __launch_bounds__(256) void k_transWh(const float* __restrict__ Wh,
                                                 ushort* __restrict__ WhT) {
  __shared__ float Ls[64][65];
  int z = blockIdx.z;
  int d0 = blockIdx.x * 64, i0 = blockIdx.y * 64;
  int tid = threadIdx.x;
  int rr = tid >> 4, c = (tid & 15) * 4;
#pragma unroll
  for (int p = 0; p < 4; ++p) {
    int row = p * 16 + rr;
    float4 v = *(const float4*)&Wh[(long)(z * NN + i0 + row) * DD + d0 + c];
    Ls[row][c] = v.x; Ls[row][c + 1] = v.y; Ls[row][c + 2] = v.z; Ls[row][c + 3] = v.w;
  }
  __syncthreads();
  int r2 = tid >> 3, cc = (tid & 7) * 8;
#pragma unroll
  for (int p = 0; p < 2; ++p) {
    int d = p * 32 + r2;
    uint4 q;
    q.x = pack2(Ls[cc + 0][d], Ls[cc + 1][d]);
    q.y = pack2(Ls[cc + 2][d], Ls[cc + 3][d]);
    q.z = pack2(Ls[cc + 4][d], Ls[cc + 5][d]);
    q.w = pack2(Ls[cc + 6][d], Ls[cc + 7][d]);
    *(uint4*)&WhT[(long)z * DD * NN + (long)(d0 + d) * NN + i0 + cc] = q;
  }
}

// ---------------- MFMA GEMM: C[i][n] = op( A[i][:] (bf16) @ BT[n][:]^T ) ----------------
// BM=64, BN=128, BK=64, 4 waves (each 32x64). XOR-swizzled bf16 LDS, ds_read_b128 frags.
// SM: A element a -> exp(a - mf[k]) * li[k] (softmax over the K axis, per-column stats).
template <int K, bool SM, bool ELU>
__global__ __launch_bounds__(256) void k_mm(const float* __restrict__ A,
                                            const ushort* __restrict__ BT,
                                            const float* __restrict__ mf,
                                            const float* __restrict__ li,
                                            float* __restrict__ C,
                                            long sAz, long sBz, long sCz) {
  __shared__ uint4 AswQ[64 * 8];    // [row][slot^(row&7)]  8 bf16 per slot
  __shared__ uint4 BswQ[128 * 8];
  int z = blockIdx.z;
  const float* Ab = A + (long)z * sAz;
  const ushort* Bb = BT + (long)z * sBz;
  float* Cb = C + (long)z * sCz;
  const float* mfb = mf + (long)z * NN;
  const float* lib = li + (long)z * NN;
  int i0 = blockIdx.y * 64;
  int n0 = blockIdx.x * 128;
  int tid = threadIdx.x;
  int r = tid >> 3, cs = tid & 7;
  int lane = tid & 63, wid = tid >> 6;
  int wm = wid >> 1, wn = wid & 1;
  int lr = lane & 15, g = lane >> 4;
  f32x4 acc[2][4] = {};
  for (int k0 = 0; k0 < K; k0 += 64) {
    // stage A: 64 rows x 64 k, f32 -> bf16 (+ optional softmax transform)
#pragma unroll
    for (int p = 0; p < 2; ++p) {
      int row = p * 32 + r;
      const float* src = Ab + (long)(i0 + row) * K + k0 + cs * 8;
      float4 v0 = *(const float4*)src;
      float4 v1 = *(const float4*)(src + 4);
      if (SM) {
        const float* mp = mfb + k0 + cs * 8;
        const float* lp = lib + k0 + cs * 8;
        float4 m0 = *(const float4*)mp, m1 = *(const float4*)(mp + 4);
        float4 l0 = *(const float4*)lp, l1 = *(const float4*)(lp + 4);
        v0.x = __expf(v0.x - m0.x) * l0.x;
        v0.y = __expf(v0.y - m0.y) * l0.y;
        v0.z = __expf(v0.z - m0.z) * l0.z;
        v0.w = __expf(v0.w - m0.w) * l0.w;
        v1.x = __expf(v1.x - m1.x) * l1.x;
        v1.y = __expf(v1.y - m1.y) * l1.y;
        v1.z = __expf(v1.z - m1.z) * l1.z;
        v1.w = __expf(v1.w - m1.w) * l1.w;
      }
      uint4 q;
      q.x = pack2(v0.x, v0.y);
      q.y = pack2(v0.z, v0.w);
      q.z = pack2(v1.x, v1.y);
      q.w = pack2(v1.z, v1.w);
      AswQ[row * 8 + (cs ^ (row & 7))] = q;
    }
    // stage B: 128 rows (n) x 64 k, already bf16 k-major
#pragma unroll
    for (int p = 0; p < 4; ++p) {
      int row = p * 32 + r;
      uint4 q = *(const uint4*)(Bb + (long)(n0 + row) * K + k0 + cs * 8);
      BswQ[row * 8 + (cs ^ (row & 7))] = q;
    }
    __syncthreads();
#pragma unroll
    for (int ks = 0; ks < 2; ++ks) {
      short8v af[2], bfr[4];
      int slot = ks * 4 + g;
#pragma unroll
      for (int mi = 0; mi < 2; ++mi) {
        int row = wm * 32 + mi * 16 + lr;
        af[mi] = *reinterpret_cast<const short8v*>(&AswQ[row * 8 + (slot ^ (row & 7))]);
      }
#pragma unroll
      for (int ni = 0; ni < 4; ++ni) {
        int row = wn * 64 + ni * 16 + lr;
        bfr[ni] = *reinterpret_cast<const short8v*>(&BswQ[row * 8 + (slot ^ (row & 7))]);
      }
#pragma unroll
      for (int mi = 0; mi < 2; ++mi)
#pragma unroll
        for (int ni = 0; ni < 4; ++ni)
          acc[mi][ni] = __builtin_amdgcn_mfma_f32_16x16x32_bf16(af[mi], bfr[ni], acc[mi][ni], 0, 0, 0);
    }
    __syncthreads();
  }
#pragma unroll
  for (int mi = 0; mi < 2; ++mi)
#pragma unroll
    for (int ni = 0; ni < 4; ++ni) {
#pragma unroll
      for (int q = 0; q < 4; ++q) {
        int row = i0 + wm * 32 + mi * 16 + g * 4 + q;
        int col = n0 + wn * 64 + ni * 16 + lr;
        float x = acc[mi][ni][q];
        if (ELU) x = x > 0.f ? x : expm1f(x);
        Cb[(long)row * DD + col] = x;
      }
    }
}

// ---------------- per-node projections ----------------
__global__ __launch_bounds__(256) void k_proj(const float* __restrict__ Wh0,
                                              const float* __restrict__ Wh1,
                                              const float* __restrict__ a,
                                              const float* __restrict__ A_rel,
                                              float* __restrict__ s0, float* __restrict__ s1,
                                              float* __restrict__ r0, float* __restrict__ r1) {
  int wid = (blockIdx.x * 256 + threadIdx.x) >> 6;
  int lane = threadIdx.x & 63;
  int mat = wid >> 13;
  int row = wid & (BN - 1);
  const float* Wh = mat ? Wh1 : Wh0;
  float4 h4 = *(const float4*)&Wh[row * DD + lane * 4];
  {
    float4 v4 = *(const float4*)&a[mat * DD + lane * 4];
    float p = h4.x * v4.x + h4.y * v4.y + h4.z * v4.z + h4.w * v4.w;
#pragma unroll
    for (int off = 32; off; off >>= 1) p += __shfl_xor(p, off);
    if (lane == 0) (mat ? s1 : s0)[row] = p;
  }
  for (int r = 0; r < RR; ++r) {
    float4 w4 = *(const float4*)&A_rel[r * 2 * DD + mat * DD + lane * 4];
    float q = h4.x * w4.x + h4.y * w4.y + h4.z * w4.z + h4.w * w4.w;
#pragma unroll
    for (int off = 32; off; off >>= 1) q += __shfl_xor(q, off);
    if (lane == 0) (mat ? r1 : r0)[r * BN + row] = q;
  }
}

// ---------------- scores + partial column-softmax stats ----------------
#define ICH 16
#define CCH 64
__global__ __launch_bounds__(128) void k_scores(const int* __restrict__ madj,
                                                const int* __restrict__ adj,
                                                const float* __restrict__ s0,
                                                const float* __restrict__ s1,
                                                const float* __restrict__ r0,
                                                const float* __restrict__ r1,
                                                float* __restrict__ S,
                                                float* __restrict__ pm,
                                                float* __restrict__ pl) {
  int b = blockIdx.y, c = blockIdx.z;
  int j = blockIdx.x * 256 + threadIdx.x * 2;
  int i0 = c * ICH;
  __shared__ float s0c[ICH];
  __shared__ float r0c[RR][ICH];
  for (int t = threadIdx.x; t < (RR + 1) * ICH; t += 128) {
    int v = t / ICH, i = t % ICH;
    float x = (v == 0) ? s0[b * NN + i0 + i] : r0[(v - 1) * BN + b * NN + i0 + i];
    if (v == 0) s0c[i] = x; else r0c[v - 1][i] = x;
  }
  __syncthreads();
  float s1a = s1[b * NN + j], s1b = s1[b * NN + j + 1];
  float r1a[RR], r1b[RR];
#pragma unroll
  for (int r = 0; r < RR; ++r) {
    r1a[r] = r1[r * BN + b * NN + j];
    r1b[r] = r1[r * BN + b * NN + j + 1];
  }
  float m0 = -3.0e38f, l0 = 0.f, m1 = -3.0e38f, l1 = 0.f;
  for (int i = 0; i < ICH; ++i) {
    int ii = i0 + i;
    int base = (b * NN + ii) * NN + j;
    int2 av = *(const int2*)&adj[base];
    float s0v = s0c[i];
    float e0 = s0v + s1a; e0 = e0 >= 0.f ? e0 : 0.2f * e0;
    float e1 = s0v + s1b; e1 = e1 >= 0.f ? e1 : 0.2f * e1;
    float sc0 = av.x > 0 ? e0 : -9e15f;
    float sc1 = av.y > 0 ? e1 : -9e15f;
    float rel0 = 0.f, rel1 = 0.f;
#pragma unroll
    for (int r = 0; r < RR; ++r) {
      int2 mv = *(const int2*)&madj[((r * BB + b) * NN + ii) * NN + j];
      float t0 = r0c[r][i] + r1a[r]; t0 = t0 >= 0.f ? t0 : 0.2f * t0;
      float t1 = r0c[r][i] + r1b[r]; t1 = t1 >= 0.f ? t1 : 0.2f * t1;
      if (mv.x > 0) rel0 += t0;
      if (mv.y > 0) rel1 += t1;
    }
    sc0 += 0.01f * rel0;
    sc1 += 0.01f * rel1;
    *(float2*)&S[base] = make_float2(sc0, sc1);
    float nm0 = fmaxf(m0, sc0);
    l0 = l0 * __expf(m0 - nm0) + __expf(sc0 - nm0); m0 = nm0;
    float nm1 = fmaxf(m1, sc1);
    l1 = l1 * __expf(m1 - nm1) + __expf(sc1 - nm1); m1 = nm1;
  }
  int col = b * NN + j;
  *(float2*)&pm[c * BN + col] = make_float2(m0, m1);
  *(float2*)&pl[c * BN + col] = make_float2(l0, l1);
}

// ---------------- combine partial stats ----------------
__global__ __launch_bounds__(256) void k_combine(const float* __restrict__ pm,
                                                 const float* __restrict__ pl,
                                                 float* __restrict__ mf,
                                                 float* __restrict__ li) {
  int col = blockIdx.x * 256 + threadIdx.x;
  float m = -3.0e38f;
  for (int c = 0; c < CCH; ++c) m = fmaxf(m, pm[c * BN + col]);
  float l = 0.f;
  for (int c = 0; c < CCH; ++c) l += pl[c * BN + col] * __expf(pm[c * BN + col] - m);
  mf[col] = m;
  li[col] = 1.0f / l;
}

extern "C" void kernel_launch(void* const* d_in, const int* in_sizes, int n_in,
                              void* d_out, int out_size, void* d_ws, size_t ws_size,
                              hipStream_t stream) {
  const float* h0 = (const float*)d_in[0];
  const float* h1 = (const float*)d_in[1];
  const int* madj = (const int*)d_in[2];
  const int* adj = (const int*)d_in[3];
  const float* W = (const float*)d_in[4];
  const float* a = (const float*)d_in[5];
  const float* A_rel = (const float*)d_in[6];
  float* out = (float*)d_out;

  float* ws = (float*)d_ws;
  float* Wh0 = ws;                        // 2M f32
  float* Wh1 = Wh0 + (size_t)BN * DD;     // 2M
  float* S = Wh1 + (size_t)BN * DD;       // 8.4M
  float* s0 = S + (size_t)BB * NN * NN;   // 8K
  float* s1 = s0 + BN;
  float* r0 = s1 + BN;                    // 96K
  float* r1 = r0 + RR * BN;
  float* pm = r1 + RR * BN;               // 512K
  float* pl = pm + (size_t)CCH * BN;
  float* mf = pl + (size_t)CCH * BN;      // 8K
  float* li = mf + BN;
  ushort* WTb = (ushort*)(li + BN);       // 64K ushort
  ushort* WhbT = WTb + DD * DD;           // 2M ushort

  k_prepW<<<dim3(4, 4), 256, 0, stream>>>(W, WTb);
  k_mm<DD, false, false><<<dim3(2, BN / 64, 1), 256, 0, stream>>>(h0, WTb, mf, li, Wh0, 0, 0, 0);
  k_mm<DD, false, false><<<dim3(2, BN / 64, 1), 256, 0, stream>>>(h1, WTb, mf, li, Wh1, 0, 0, 0);
  k_transWh<<<dim3(4, 16, 8), 256, 0, stream>>>(Wh1, WhbT);
  k_proj<<<(2 * BN) / 4, 256, 0, stream>>>(Wh0, Wh1, a, A_rel, s0, s1, r0, r1);
  k_scores<<<dim3(NN / 256, BB, CCH), 128, 0, stream>>>(madj, adj, s0, s1, r0, r1, S, pm, pl);
  k_combine<<<BN / 256, 256, 0, stream>>>(pm, pl, mf, li);
  k_mm<NN, true, true><<<dim3(2, NN / 64, BB), 256, 0, stream>>>(
      S, WhbT, mf, li, out, (long)NN * NN, (long)DD * NN, (long)NN * DD);
}

// Round 3
// 200.778 us; speedup vs baseline: 1.4941x; 1.1880x over previous
//
#include <hip/hip_runtime.h>
#include <hip/hip_bf16.h>

#define BB 8
#define NN 1024
#define DD 256
#define RR 12
#define BN (BB * NN)  // 8192
#define ICH 8
#define CCH (NN / ICH)  // 128

typedef __attribute__((ext_vector_type(8))) short short8v;
typedef __attribute__((ext_vector_type(4))) float f32x4;

static __device__ __forceinline__ ushort f2bf(float f) {
  union { float f; uint u; } v; v.f = f;
  uint r = v.u + 0x7FFF + ((v.u >> 16) & 1);
  return (ushort)(r >> 16);
}
static __device__ __forceinline__ uint pack2(float a, float b) {
  return (uint)f2bf(a) | ((uint)f2bf(b) << 16);
}

// ---------------- prep: WTb[d][k] = bf16(W[k][d]) ----------------
__global__ __launch_bounds__(256) void k_prepW(const float* __restrict__ W,
                                               ushort* __restrict__ WTb) {
  __shared__ float Ls[64][65];
  int k0 = blockIdx.x * 64, d0 = blockIdx.y * 64;
  int tid = threadIdx.x;
  int rr = tid >> 4, c = (tid & 15) * 4;
#pragma unroll
  for (int p = 0; p < 4; ++p) {
    int row = p * 16 + rr;
    float4 v = *(const float4*)&W[(k0 + row) * DD + d0 + c];
    Ls[row][c] = v.x; Ls[row][c + 1] = v.y; Ls[row][c + 2] = v.z; Ls[row][c + 3] = v.w;
  }
  __syncthreads();
  int r2 = tid >> 3, cc = (tid & 7) * 8;
#pragma unroll
  for (int p = 0; p < 2; ++p) {
    int d = p * 32 + r2;
    uint4 q;
    q.x = pack2(Ls[cc + 0][d], Ls[cc + 1][d]);
    q.y = pack2(Ls[cc + 2][d], Ls[cc + 3][d]);
    q.z = pack2(Ls[cc + 4][d], Ls[cc + 5][d]);
    q.w = pack2(Ls[cc + 6][d], Ls[cc + 7][d]);
    *(uint4*)&WTb[(d0 + d) * DD + k0 + cc] = q;
  }
}

// ---------------- prep: WhbT[b][d][i] = bf16(Wh1[b][i][d]) ----------------
__global__ __launch_bounds__(256) void k_transWh(const float* __restrict__ Wh,
                                                 ushort* __restrict__ WhT) {
  __shared__ float Ls[64][65];
  int z = blockIdx.z;
  int d0 = blockIdx.x * 64, i0 = blockIdx.y * 64;
  int tid = threadIdx.x;
  int rr = tid >> 4, c = (tid & 15) * 4;
#pragma unroll
  for (int p = 0; p < 4; ++p) {
    int row = p * 16 + rr;
    float4 v = *(const float4*)&Wh[(long)(z * NN + i0 + row) * DD + d0 + c];
    Ls[row][c] = v.x; Ls[row][c + 1] = v.y; Ls[row][c + 2] = v.z; Ls[row][c + 3] = v.w;
  }
  __syncthreads();
  int r2 = tid >> 3, cc = (tid & 7) * 8;
#pragma unroll
  for (int p = 0; p < 2; ++p) {
    int d = p * 32 + r2;
    uint4 q;
    q.x = pack2(Ls[cc + 0][d], Ls[cc + 1][d]);
    q.y = pack2(Ls[cc + 2][d], Ls[cc + 3][d]);
    q.z = pack2(Ls[cc + 4][d], Ls[cc + 5][d]);
    q.w = pack2(Ls[cc + 6][d], Ls[cc + 7][d]);
    *(uint4*)&WhT[(long)z * DD * NN + (long)(d0 + d) * NN + i0 + cc] = q;
  }
}

// ---------------- MFMA GEMM: C[i][n] = op( A[i][:] (bf16) @ BT[n][:]^T ) ----------------
// BM=64, BN=128, BK=64, 4 waves. XOR-swizzled bf16 LDS, ds_read_b128 frags.
// SM: A element a -> exp(a - mf[k]) * li[k] (softmax over the K axis).
template <int K, bool SM, bool ELU, bool SPLITA>
__global__ __launch_bounds__(256) void k_mm(const float* __restrict__ A0,
                                            const float* __restrict__ A1,
                                            const ushort* __restrict__ BT,
                                            const float* __restrict__ mf,
                                            const float* __restrict__ li,
                                            float* __restrict__ C,
                                            long sAz, long sBz, long sCz) {
  __shared__ uint4 AswQ[64 * 8];
  __shared__ uint4 BswQ[128 * 8];
  int z = blockIdx.z;
  const float* Ab = SPLITA ? (z ? A1 : A0) : A0 + (long)z * sAz;
  const ushort* Bb = BT + (long)z * sBz;
  float* Cb = C + (long)z * sCz;
  const float* mfb = mf + (long)z * NN;
  const float* lib = li + (long)z * NN;
  int i0 = blockIdx.y * 64;
  int n0 = blockIdx.x * 128;
  int tid = threadIdx.x;
  int r = tid >> 3, cs = tid & 7;
  int lane = tid & 63, wid = tid >> 6;
  int wm = wid >> 1, wn = wid & 1;
  int lr = lane & 15, g = lane >> 4;
  f32x4 acc[2][4] = {};
  for (int k0 = 0; k0 < K; k0 += 64) {
#pragma unroll
    for (int p = 0; p < 2; ++p) {
      int row = p * 32 + r;
      const float* src = Ab + (long)(i0 + row) * K + k0 + cs * 8;
      float4 v0 = *(const float4*)src;
      float4 v1 = *(const float4*)(src + 4);
      if (SM) {
        const float* mp = mfb + k0 + cs * 8;
        const float* lp = lib + k0 + cs * 8;
        float4 m0 = *(const float4*)mp, m1 = *(const float4*)(mp + 4);
        float4 l0 = *(const float4*)lp, l1 = *(const float4*)(lp + 4);
        v0.x = __expf(v0.x - m0.x) * l0.x;
        v0.y = __expf(v0.y - m0.y) * l0.y;
        v0.z = __expf(v0.z - m0.z) * l0.z;
        v0.w = __expf(v0.w - m0.w) * l0.w;
        v1.x = __expf(v1.x - m1.x) * l1.x;
        v1.y = __expf(v1.y - m1.y) * l1.y;
        v1.z = __expf(v1.z - m1.z) * l1.z;
        v1.w = __expf(v1.w - m1.w) * l1.w;
      }
      uint4 q;
      q.x = pack2(v0.x, v0.y);
      q.y = pack2(v0.z, v0.w);
      q.z = pack2(v1.x, v1.y);
      q.w = pack2(v1.z, v1.w);
      AswQ[row * 8 + (cs ^ (row & 7))] = q;
    }
#pragma unroll
    for (int p = 0; p < 4; ++p) {
      int row = p * 32 + r;
      uint4 q = *(const uint4*)(Bb + (long)(n0 + row) * K + k0 + cs * 8);
      BswQ[row * 8 + (cs ^ (row & 7))] = q;
    }
    __syncthreads();
#pragma unroll
    for (int ks = 0; ks < 2; ++ks) {
      short8v af[2], bfr[4];
      int slot = ks * 4 + g;
#pragma unroll
      for (int mi = 0; mi < 2; ++mi) {
        int row = wm * 32 + mi * 16 + lr;
        af[mi] = *reinterpret_cast<const short8v*>(&AswQ[row * 8 + (slot ^ (row & 7))]);
      }
#pragma unroll
      for (int ni = 0; ni < 4; ++ni) {
        int row = wn * 64 + ni * 16 + lr;
        bfr[ni] = *reinterpret_cast<const short8v*>(&BswQ[row * 8 + (slot ^ (row & 7))]);
      }
#pragma unroll
      for (int mi = 0; mi < 2; ++mi)
#pragma unroll
        for (int ni = 0; ni < 4; ++ni)
          acc[mi][ni] = __builtin_amdgcn_mfma_f32_16x16x32_bf16(af[mi], bfr[ni], acc[mi][ni], 0, 0, 0);
    }
    __syncthreads();
  }
#pragma unroll
  for (int mi = 0; mi < 2; ++mi)
#pragma unroll
    for (int ni = 0; ni < 4; ++ni) {
#pragma unroll
      for (int q = 0; q < 4; ++q) {
        int row = i0 + wm * 32 + mi * 16 + g * 4 + q;
        int col = n0 + wn * 64 + ni * 16 + lr;
        float x = acc[mi][ni][q];
        if (ELU) x = x > 0.f ? x : expm1f(x);
        Cb[(long)row * DD + col] = x;
      }
    }
}

// ---------------- per-node projections ----------------
__global__ __launch_bounds__(256) void k_proj(const float* __restrict__ Wh0,
                                              const float* __restrict__ Wh1,
                                              const float* __restrict__ a,
                                              const float* __restrict__ A_rel,
                                              float* __restrict__ s0, float* __restrict__ s1,
                                              float* __restrict__ r0, float* __restrict__ r1) {
  int wid = (blockIdx.x * 256 + threadIdx.x) >> 6;
  int lane = threadIdx.x & 63;
  int mat = wid >> 13;
  int row = wid & (BN - 1);
  const float* Wh = mat ? Wh1 : Wh0;
  float4 h4 = *(const float4*)&Wh[row * DD + lane * 4];
  {
    float4 v4 = *(const float4*)&a[mat * DD + lane * 4];
    float p = h4.x * v4.x + h4.y * v4.y + h4.z * v4.z + h4.w * v4.w;
#pragma unroll
    for (int off = 32; off; off >>= 1) p += __shfl_xor(p, off);
    if (lane == 0) (mat ? s1 : s0)[row] = p;
  }
  for (int r = 0; r < RR; ++r) {
    float4 w4 = *(const float4*)&A_rel[r * 2 * DD + mat * DD + lane * 4];
    float q = h4.x * w4.x + h4.y * w4.y + h4.z * w4.z + h4.w * w4.w;
#pragma unroll
    for (int off = 32; off; off >>= 1) q += __shfl_xor(q, off);
    if (lane == 0) (mat ? r1 : r0)[r * BN + row] = q;
  }
}

// ---------------- scores + partial column-softmax stats ----------------
// Block = 256 threads = full j-row (4 cols/thread, int4 loads), ICH=8 rows.
// r OUTER: streams 32KB contiguous per relation slab -> no cross-slab
// same-bank row thrash. rel sums in registers (static indexing).
__global__ __launch_bounds__(256) void k_scores(const int* __restrict__ madj,
                                                const int* __restrict__ adj,
                                                const float* __restrict__ s0,
                                                const float* __restrict__ s1,
                                                const float* __restrict__ r0,
                                                const float* __restrict__ r1,
                                                float* __restrict__ S,
                                                float* __restrict__ pm,
                                                float* __restrict__ pl) {
  int b = blockIdx.x, c = blockIdx.y;
  int tid = threadIdx.x;
  int j4 = tid * 4;
  int i0 = c * ICH;
  __shared__ float s0c[ICH];
  __shared__ float r0c[RR][ICH];
  if (tid < (RR + 1) * ICH) {
    int v = tid / ICH, i = tid % ICH;
    float x = (v == 0) ? s0[b * NN + i0 + i] : r0[(v - 1) * BN + b * NN + i0 + i];
    if (v == 0) s0c[i] = x; else r0c[v - 1][i] = x;
  }
  __syncthreads();
  float4 s14 = *(const float4*)&s1[b * NN + j4];
  float rel[ICH][4] = {};
  for (int r = 0; r < RR; ++r) {
    float4 r1v = *(const float4*)&r1[r * BN + b * NN + j4];
#pragma unroll
    for (int i = 0; i < ICH; ++i) {
      int4 mv = *(const int4*)&madj[(((long)r * BB + b) * NN + i0 + i) * NN + j4];
      float r0v = r0c[r][i];
      float t0 = r0v + r1v.x; t0 = t0 >= 0.f ? t0 : 0.2f * t0;
      float t1 = r0v + r1v.y; t1 = t1 >= 0.f ? t1 : 0.2f * t1;
      float t2 = r0v + r1v.z; t2 = t2 >= 0.f ? t2 : 0.2f * t2;
      float t3 = r0v + r1v.w; t3 = t3 >= 0.f ? t3 : 0.2f * t3;
      if (mv.x > 0) rel[i][0] += t0;
      if (mv.y > 0) rel[i][1] += t1;
      if (mv.z > 0) rel[i][2] += t2;
      if (mv.w > 0) rel[i][3] += t3;
    }
  }
  float m0 = -3.0e38f, m1 = -3.0e38f, m2 = -3.0e38f, m3 = -3.0e38f;
  float l0 = 0.f, l1 = 0.f, l2 = 0.f, l3 = 0.f;
#pragma unroll
  for (int i = 0; i < ICH; ++i) {
    int4 av = *(const int4*)&adj[((long)b * NN + i0 + i) * NN + j4];
    float s0v = s0c[i];
    float4 sc;
    {
      float e = s0v + s14.x; e = e >= 0.f ? e : 0.2f * e;
      sc.x = (av.x > 0 ? e : -9e15f) + 0.01f * rel[i][0];
    }
    {
      float e = s0v + s14.y; e = e >= 0.f ? e : 0.2f * e;
      sc.y = (av.y > 0 ? e : -9e15f) + 0.01f * rel[i][1];
    }
    {
      float e = s0v + s14.z; e = e >= 0.f ? e : 0.2f * e;
      sc.z = (av.z > 0 ? e : -9e15f) + 0.01f * rel[i][2];
    }
    {
      float e = s0v + s14.w; e = e >= 0.f ? e : 0.2f * e;
      sc.w = (av.w > 0 ? e : -9e15f) + 0.01f * rel[i][3];
    }
    *(float4*)&S[((long)b * NN + i0 + i) * NN + j4] = sc;
    float nm;
    nm = fmaxf(m0, sc.x); l0 = l0 * __expf(m0 - nm) + __expf(sc.x - nm); m0 = nm;
    nm = fmaxf(m1, sc.y); l1 = l1 * __expf(m1 - nm) + __expf(sc.y - nm); m1 = nm;
    nm = fmaxf(m2, sc.z); l2 = l2 * __expf(m2 - nm) + __expf(sc.z - nm); m2 = nm;
    nm = fmaxf(m3, sc.w); l3 = l3 * __expf(m3 - nm) + __expf(sc.w - nm); m3 = nm;
  }
  *(float4*)&pm[(long)c * BN + b * NN + j4] = make_float4(m0, m1, m2, m3);
  *(float4*)&pl[(long)c * BN + b * NN + j4] = make_float4(l0, l1, l2, l3);
}

// ---------------- combine partial stats ----------------
__global__ __launch_bounds__(256) void k_combine(const float* __restrict__ pm,
                                                 const float* __restrict__ pl,
                                                 float* __restrict__ mf,
                                                 float* __restrict__ li) {
  int col = blockIdx.x * 256 + threadIdx.x;
  float m = -3.0e38f;
#pragma unroll 8
  for (int c = 0; c < CCH; ++c) m = fmaxf(m, pm[(long)c * BN + col]);
  float l = 0.f;
#pragma unroll 8
  for (int c = 0; c < CCH; ++c) l += pl[(long)c * BN + col] * __expf(pm[(long)c * BN + col] - m);
  mf[col] = m;
  li[col] = 1.0f / l;
}

extern "C" void kernel_launch(void* const* d_in, const int* in_sizes, int n_in,
                              void* d_out, int out_size, void* d_ws, size_t ws_size,
                              hipStream_t stream) {
  const float* h0 = (const float*)d_in[0];
  const float* h1 = (const float*)d_in[1];
  const int* madj = (const int*)d_in[2];
  const int* adj = (const int*)d_in[3];
  const float* W = (const float*)d_in[4];
  const float* a = (const float*)d_in[5];
  const float* A_rel = (const float*)d_in[6];
  float* out = (float*)d_out;

  float* ws = (float*)d_ws;
  float* Wh0 = ws;                        // 2M f32
  float* Wh1 = Wh0 + (size_t)BN * DD;     // 2M
  float* S = Wh1 + (size_t)BN * DD;       // 8.4M
  float* s0 = S + (size_t)BB * NN * NN;   // 8K
  float* s1 = s0 + BN;
  float* r0 = s1 + BN;                    // 96K
  float* r1 = r0 + RR * BN;
  float* pm = r1 + RR * BN;               // 1M
  float* pl = pm + (size_t)CCH * BN;      // 1M
  float* mf = pl + (size_t)CCH * BN;      // 8K
  float* li = mf + BN;
  ushort* WTb = (ushort*)(li + BN);       // 64K ushort
  ushort* WhbT = WTb + DD * DD;           // 2M ushort

  k_prepW<<<dim3(4, 4), 256, 0, stream>>>(W, WTb);
  k_mm<DD, false, false, true><<<dim3(2, BN / 64, 2), 256, 0, stream>>>(
      h0, h1, WTb, mf, li, Wh0, 0, 0, (long)BN * DD);
  k_transWh<<<dim3(4, 16, 8), 256, 0, stream>>>(Wh1, WhbT);
  k_proj<<<(2 * BN) / 4, 256, 0, stream>>>(Wh0, Wh1, a, A_rel, s0, s1, r0, r1);
  k_scores<<<dim3(BB, CCH), 256, 0, stream>>>(madj, adj, s0, s1, r0, r1, S, pm, pl);
  k_combine<<<BN / 256, 256, 0, stream>>>(pm, pl, mf, li);
  k_mm<NN, true, true, false><<<dim3(2, NN / 64, BB), 256, 0, stream>>>(
      S, S, WhbT, mf, li, out, (long)NN * NN, (long)DD * NN, (long)NN * DD);
}